// Round 3
// baseline (1688.739 us; speedup 1.0000x reference)
//
#include <hip/hip_runtime.h>
#include <hip/hip_bf16.h>
#include <math.h>

typedef __hip_bfloat16 bf16;
typedef __attribute__((ext_vector_type(4))) float v_f32x4;
typedef __attribute__((ext_vector_type(4))) unsigned short v_u16x4;
typedef __attribute__((ext_vector_type(8))) unsigned short v_u16x8;
typedef __attribute__((ext_vector_type(8))) __bf16 v_bf16x8;

#define NB 2
#define NT 2048
#define ND 1024
#define NH 16
#define NSC 64
#define NST 16
#define NM (NB*NT)
#define RMS_EPS 1.1920929e-07f

__device__ inline float b2f(unsigned short u) {
  union { unsigned int i; float f; } v; v.i = ((unsigned int)u) << 16; return v.f;
}
__device__ inline unsigned short f2b(float f) {  // RNE f32->bf16
  union { float f; unsigned int i; } v; v.f = f;
  unsigned int r = (v.i + 0x7FFF + ((v.i >> 16) & 1)) >> 16;
  return (unsigned short)r;
}

// async global->LDS, 16B per lane; LDS dest = wave-uniform base + lane*16
__device__ inline void gl_lds16(const bf16* g, bf16* l) {
  __builtin_amdgcn_global_load_lds((__attribute__((address_space(1))) void*)g,
                                   (__attribute__((address_space(3))) void*)l,
                                   16, 0, 0);
}

// ---------------- f32 -> bf16 conversion (weights) ----------------
__global__ __launch_bounds__(256) void cvt_kernel(const float* __restrict__ src,
                                                  bf16* __restrict__ dst, int n4) {
  int i = blockIdx.x * 256 + threadIdx.x;
  if (i < n4) {
    v_f32x4 v = ((const v_f32x4*)src)[i];
    v_u16x4 o;
    o[0] = f2b(v[0]); o[1] = f2b(v[1]); o[2] = f2b(v[2]); o[3] = f2b(v[3]);
    ((v_u16x4*)dst)[i] = o;
  }
}

// ---------------- RMSNorm: f32 in, f32 weight, bf16 out ----------------
__global__ __launch_bounds__(256) void rmsnorm_kernel(
    const float* __restrict__ x, const float* __restrict__ w, bf16* __restrict__ out) {
  const int row = blockIdx.x;
  const int t = threadIdx.x;
  v_f32x4 xv = *(const v_f32x4*)(x + (size_t)row * ND + t * 4);
  float s = xv[0]*xv[0] + xv[1]*xv[1] + xv[2]*xv[2] + xv[3]*xv[3];
  #pragma unroll
  for (int off = 32; off; off >>= 1) s += __shfl_xor(s, off, 64);
  __shared__ float red[4];
  __shared__ float scale_s;
  if ((t & 63) == 0) red[t >> 6] = s;
  __syncthreads();
  if (t == 0) {
    float tot = red[0] + red[1] + red[2] + red[3];
    scale_s = rsqrtf(tot * (1.0f / ND) + RMS_EPS);
  }
  __syncthreads();
  float sc = scale_s;
  v_f32x4 wv = *(const v_f32x4*)(w + t * 4);
  unsigned short* orow = (unsigned short*)out + (size_t)row * ND + t * 4;
  v_u16x4 o;
  o[0] = f2b(xv[0] * sc * wv[0]);
  o[1] = f2b(xv[1] * sc * wv[1]);
  o[2] = f2b(xv[2] * sc * wv[2]);
  o[3] = f2b(xv[3] * sc * wv[3]);
  *(v_u16x4*)orow = o;
}

// ---------------- GEMM: C[M,N] = A[M,K(lda)] @ Bw[N,K]^T (+res f32) ----------------
template <bool RES, bool OUTF32>
__global__ __launch_bounds__(256) void gemm_bt_kernel(
    const bf16* __restrict__ A, const bf16* __restrict__ Bw,
    const float* __restrict__ res, void* __restrict__ Cout, int N, int K, int lda) {
  __shared__ alignas(16) bf16 As[128 * 32];
  __shared__ alignas(16) bf16 Bs[128 * 32];
  const int tid = threadIdx.x;
  const int wid = tid >> 6;
  const int lane = tid & 63;
  const int c = lane & 15;
  const int quad = lane >> 4;
  const int m0 = blockIdx.y * 128;
  const int n0 = blockIdx.x * 128;
  const int wm = (wid >> 1) * 64;
  const int wn = (wid & 1) * 64;
  const int srow = tid >> 2;
  const int schunk = tid & 3;

  const bf16* Ap0 = A + (size_t)(m0 + srow) * lda + schunk * 8;
  const bf16* Ap1 = Ap0 + (size_t)64 * lda;
  const bf16* Bp0 = Bw + (size_t)(n0 + srow) * K + schunk * 8;
  const bf16* Bp1 = Bp0 + (size_t)64 * K;
  bf16* AsW0 = As + wid * 512;
  bf16* AsW1 = As + 2048 + wid * 512;
  bf16* BsW0 = Bs + wid * 512;
  bf16* BsW1 = Bs + 2048 + wid * 512;

  v_f32x4 acc[4][4];
  #pragma unroll
  for (int i = 0; i < 4; i++)
    #pragma unroll
    for (int j = 0; j < 4; j++)
      #pragma unroll
      for (int r = 0; r < 4; r++) acc[i][j][r] = 0.0f;

  const int nk = K >> 5;
  for (int kt = 0; kt < nk; kt++) {
    gl_lds16(Ap0 + kt * 32, AsW0);
    gl_lds16(Ap1 + kt * 32, AsW1);
    gl_lds16(Bp0 + kt * 32, BsW0);
    gl_lds16(Bp1 + kt * 32, BsW1);
    __syncthreads();
    v_bf16x8 af[4], bfw[4];
    #pragma unroll
    for (int i = 0; i < 4; i++)
      af[i] = *(const v_bf16x8*)&As[(wm + i * 16 + c) * 32 + quad * 8];
    #pragma unroll
    for (int j = 0; j < 4; j++)
      bfw[j] = *(const v_bf16x8*)&Bs[(wn + j * 16 + c) * 32 + quad * 8];
    #pragma unroll
    for (int i = 0; i < 4; i++)
      #pragma unroll
      for (int j = 0; j < 4; j++)
        acc[i][j] = __builtin_amdgcn_mfma_f32_16x16x32_bf16(af[i], bfw[j], acc[i][j], 0, 0, 0);
    __syncthreads();
  }

  #pragma unroll
  for (int i = 0; i < 4; i++)
    #pragma unroll
    for (int j = 0; j < 4; j++)
      #pragma unroll
      for (int r = 0; r < 4; r++) {
        int rg = m0 + wm + i * 16 + quad * 4 + r;
        int cg = n0 + wn + j * 16 + c;
        size_t idx = (size_t)rg * N + cg;
        float v = acc[i][j][r];
        if (RES) v += res[idx];
        if (OUTF32) ((float*)Cout)[idx] = v;
        else ((bf16*)Cout)[idx] = __float2bfloat16(v);
      }
}

// ---------------- Flash attention (causal), MFMA QK^T and PV ----------------
__global__ __launch_bounds__(256) void attn_kernel(const bf16* __restrict__ qkv,
                                                   bf16* __restrict__ out) {
  __shared__ alignas(16) bf16 Qs[64 * 72];
  __shared__ alignas(16) bf16 Ks[64 * 72];
  __shared__ alignas(16) bf16 Vt[64 * 72];
  __shared__ alignas(16) bf16 Ps[64 * 72];
  const int tid = threadIdx.x;
  const int w = tid >> 6;
  const int lane = tid & 63;
  const int c = lane & 15;
  const int quad = lane >> 4;
  const int qt = blockIdx.x;
  const int bh = blockIdx.y;
  const int b = bh >> 4;
  const int h = bh & 15;
  const int srow = tid >> 2;
  const int schunk = tid & 3;

  {  // stage Q tile [64 q][64 d]
    const bf16* src = qkv + (size_t)(b * NT + qt * 64 + srow) * 3072 + h * 64 + schunk * 16;
    v_u16x8 v0 = *(const v_u16x8*)(src);
    v_u16x8 v1 = *(const v_u16x8*)(src + 8);
    *(v_u16x8*)&Qs[srow * 72 + schunk * 16] = v0;
    *(v_u16x8*)&Qs[srow * 72 + schunk * 16 + 8] = v1;
  }
  __syncthreads();
  v_bf16x8 aq0 = *(const v_bf16x8*)&Qs[(w * 16 + c) * 72 + quad * 8];
  v_bf16x8 aq1 = *(const v_bf16x8*)&Qs[(w * 16 + c) * 72 + 32 + quad * 8];

  float m[4], l[4];
  v_f32x4 o[4];
  #pragma unroll
  for (int r = 0; r < 4; r++) { m[r] = -__builtin_inff(); l[r] = 0.0f; }
  #pragma unroll
  for (int j = 0; j < 4; j++)
    #pragma unroll
    for (int r = 0; r < 4; r++) o[j][r] = 0.0f;

  unsigned short* Vtu = (unsigned short*)Vt;

  for (int kt = 0; kt <= qt; kt++) {
    {  // stage K [64 k][64 d] and V transposed [64 d][64 k]
      const bf16* ksrc = qkv + (size_t)(b * NT + kt * 64 + srow) * 3072 + 1024 + h * 64 + schunk * 16;
      v_u16x8 k0 = *(const v_u16x8*)(ksrc);
      v_u16x8 k1 = *(const v_u16x8*)(ksrc + 8);
      *(v_u16x8*)&Ks[srow * 72 + schunk * 16] = k0;
      *(v_u16x8*)&Ks[srow * 72 + schunk * 16 + 8] = k1;
      const bf16* vsrc = qkv + (size_t)(b * NT + kt * 64 + srow) * 3072 + 2048 + h * 64 + schunk * 16;
      v_u16x8 vv0 = *(const v_u16x8*)(vsrc);
      v_u16x8 vv1 = *(const v_u16x8*)(vsrc + 8);
      #pragma unroll
      for (int dd = 0; dd < 8; dd++) Vtu[(schunk * 16 + dd) * 72 + srow] = vv0[dd];
      #pragma unroll
      for (int dd = 0; dd < 8; dd++) Vtu[(schunk * 16 + dd + 8) * 72 + srow] = vv1[dd];
    }
    __syncthreads();

    // S = Q K^T  (per wave: 16 q rows x 64 keys)
    float sv[4][4];
    const bool diag = (kt == qt);
    #pragma unroll
    for (int j = 0; j < 4; j++) {
      v_bf16x8 bk0 = *(const v_bf16x8*)&Ks[(j * 16 + c) * 72 + quad * 8];
      v_bf16x8 bk1 = *(const v_bf16x8*)&Ks[(j * 16 + c) * 72 + 32 + quad * 8];
      v_f32x4 z;
      #pragma unroll
      for (int r = 0; r < 4; r++) z[r] = 0.0f;
      z = __builtin_amdgcn_mfma_f32_16x16x32_bf16(aq0, bk0, z, 0, 0, 0);
      z = __builtin_amdgcn_mfma_f32_16x16x32_bf16(aq1, bk1, z, 0, 0, 0);
      #pragma unroll
      for (int r = 0; r < 4; r++) {
        float v = z[r] * 0.125f;
        if (diag && (j * 16 + c) > (w * 16 + quad * 4 + r)) v = -__builtin_inff();
        sv[j][r] = v;
      }
    }

    // online softmax per q row (row = quad*4+r, 16 key-lanes share a quad)
    float alpha[4], p[4][4];
    #pragma unroll
    for (int r = 0; r < 4; r++) {
      float tm = fmaxf(fmaxf(sv[0][r], sv[1][r]), fmaxf(sv[2][r], sv[3][r]));
      #pragma unroll
      for (int off = 1; off < 16; off <<= 1) tm = fmaxf(tm, __shfl_xor(tm, off, 64));
      float mn = fmaxf(m[r], tm);
      alpha[r] = __expf(m[r] - mn);
      float ps = 0.0f;
      #pragma unroll
      for (int j = 0; j < 4; j++) { float pv = __expf(sv[j][r] - mn); p[j][r] = pv; ps += pv; }
      #pragma unroll
      for (int off = 1; off < 16; off <<= 1) ps += __shfl_xor(ps, off, 64);
      l[r] = l[r] * alpha[r] + ps;
      m[r] = mn;
    }
    // write P (C-layout -> LDS -> A-layout), rescale O
    #pragma unroll
    for (int j = 0; j < 4; j++)
      #pragma unroll
      for (int r = 0; r < 4; r++) {
        Ps[(w * 16 + quad * 4 + r) * 72 + j * 16 + c] = __float2bfloat16(p[j][r]);
        o[j][r] *= alpha[r];
      }
    // O += P V
    #pragma unroll
    for (int ks = 0; ks < 2; ks++) {
      v_bf16x8 ap = *(const v_bf16x8*)&Ps[(w * 16 + c) * 72 + ks * 32 + quad * 8];
      #pragma unroll
      for (int jn = 0; jn < 4; jn++) {
        v_bf16x8 bv = *(const v_bf16x8*)&Vt[(jn * 16 + c) * 72 + ks * 32 + quad * 8];
        o[jn] = __builtin_amdgcn_mfma_f32_16x16x32_bf16(ap, bv, o[jn], 0, 0, 0);
      }
    }
    __syncthreads();
  }

  #pragma unroll
  for (int jn = 0; jn < 4; jn++)
    #pragma unroll
    for (int r = 0; r < 4; r++) {
      int qg = qt * 64 + w * 16 + quad * 4 + r;
      out[(size_t)(b * NT + qg) * ND + h * 64 + jn * 16 + c] =
          __float2bfloat16(o[jn][r] / l[r]);
    }
}

// ---------------- scan prep: softplus/silu/dtz from zg + P2 ----------------
__global__ __launch_bounds__(256) void scanprep_kernel(
    const bf16* __restrict__ zg, const float* __restrict__ P2, const float* __restrict__ dt_b,
    float* __restrict__ dt_a, float* __restrict__ dtz_a, float* __restrict__ gate_a) {
  const int row = blockIdx.x * 4 + (threadIdx.x >> 6);
  const int c = threadIdx.x & 63;
  const unsigned short* zgu = (const unsigned short*)zg;
  float z = b2f(zgu[(size_t)row * 128 + c]);
  float g = b2f(zgu[(size_t)row * 128 + 64 + c]);
  float a = P2[(size_t)row * 128 + c] + dt_b[c];
  float dt = (a > 20.0f) ? a : log1pf(__expf(a));
  dt_a[(size_t)row * NSC + c] = dt;
  dtz_a[(size_t)row * NSC + c] = dt * z;
  gate_a[(size_t)row * NSC + c] = g / (1.0f + __expf(-g));
}

// ---------------- selective scan (sequential over T) ----------------
__global__ __launch_bounds__(1024) void scan_kernel(
    const float* __restrict__ dt, const float* __restrict__ dtz,
    const float* __restrict__ P2, const float* __restrict__ gate,
    const float* __restrict__ A_log, bf16* __restrict__ ys) {
  const int b = blockIdx.x;
  const int tid = threadIdx.x;
  const int sc = tid >> 4;
  const int st = tid & 15;
  const float A = -__expf(A_log[sc * NST + st]);
  float state = 0.0f;
  const float* dtp  = dt  + (size_t)b * NT * NSC + sc;
  const float* dtzp = dtz + (size_t)b * NT * NSC + sc;
  const float* bip  = P2  + (size_t)b * NT * 128 + 64 + st;
  const float* cip  = P2  + (size_t)b * NT * 128 + 80 + st;
  const float* gp   = gate + (size_t)b * NT * NSC + sc;
  bf16* yp = ys + (size_t)b * NT * NSC + sc;
  #pragma unroll 4
  for (int t = 0; t < NT; t++) {
    float d  = dtp[(size_t)t * NSC];
    float dz = dtzp[(size_t)t * NSC];
    float bv = bip[(size_t)t * 128];
    float cv = cip[(size_t)t * 128];
    state = fmaf(d, A, 1.0f) * state + dz * bv;
    float pv = state * cv;
    pv += __shfl_xor(pv, 1, 64);
    pv += __shfl_xor(pv, 2, 64);
    pv += __shfl_xor(pv, 4, 64);
    pv += __shfl_xor(pv, 8, 64);
    if (st == 0) yp[(size_t)t * NSC] = __float2bfloat16(pv * gp[(size_t)t * NSC]);
  }
}

extern "C" void kernel_launch(void* const* d_in, const int* in_sizes, int n_in,
                              void* d_out, int out_size, void* d_ws, size_t ws_size,
                              hipStream_t stream) {
  // ALL inputs are float32 (per reference); output float32.
  const float* x      = (const float*)d_in[0];
  const float* qkv_w  = (const float*)d_in[1];
  const float* o_w    = (const float*)d_in[2];
  const float* n1w    = (const float*)d_in[3];
  const float* n2w    = (const float*)d_in[4];
  const float* in_w   = (const float*)d_in[5];
  const float* out_w  = (const float*)d_in[6];
  const float* A_log  = (const float*)d_in[7];
  const float* Bp_w   = (const float*)d_in[8];
  const float* Cp_w   = (const float*)d_in[9];
  const float* dt_w   = (const float*)d_in[10];
  const float* dt_b   = (const float*)d_in[11];
  const float* gate_w = (const float*)d_in[12];
  float* out = (float*)d_out;

  char* ws = (char*)d_ws;
  size_t off = 0;
  auto alloc = [&](size_t bytes) {
    char* p = ws + off;
    off += (bytes + 255) & ~(size_t)255;
    return p;
  };
  bf16* qkvw_b = (bf16*)alloc((size_t)3 * ND * ND * 2);   // 6 MB
  bf16* ow_b   = (bf16*)alloc((size_t)ND * ND * 2);       // 2 MB
  bf16* outw_b = (bf16*)alloc((size_t)ND * NSC * 2);      // 128 KB
  bf16* W1     = (bf16*)alloc((size_t)128 * ND * 2);      // 256 KB  (in_w rows 0-63, gate_w rows 64-127)
  bf16* W2     = (bf16*)alloc((size_t)128 * NSC * 2);     // 16 KB   (dt_w 0-63, Bp_w 64-79, Cp_w 80-95, zero tail)
  char* region0 = alloc((size_t)NM * 3 * ND * 2);         // 24 MB: qkv bf16, then x1 f32 (16 MB)
  char* region1 = alloc((size_t)NM * ND * 2);             // 8 MB: h -> attnout -> h2
  bf16*  zg    = (bf16*)alloc((size_t)NM * 128 * 2);      // 1 MB
  float* P2    = (float*)alloc((size_t)NM * 128 * 4);     // 2 MB
  float* dt_a  = (float*)alloc((size_t)NM * NSC * 4);     // 1 MB
  float* dtz_a = (float*)alloc((size_t)NM * NSC * 4);     // 1 MB
  float* gate_a= (float*)alloc((size_t)NM * NSC * 4);     // 1 MB
  bf16*  ys    = (bf16*)alloc((size_t)NM * NSC * 2);      // 512 KB

  bf16*  qkv     = (bf16*)region0;
  float* x1      = (float*)region0;   // aliases qkv (dead after attn)
  bf16*  h       = (bf16*)region1;
  bf16*  attnout = (bf16*)region1;    // aliases h (dead after qkv gemm)
  bf16*  h2      = (bf16*)region1;    // aliases attnout (dead after o gemm)

  // weight conversions (every launch; no static state)
  hipMemsetAsync(W2, 0, (size_t)128 * NSC * 2, stream);
  auto cvt = [&](const float* s, bf16* d, int n) {
    int n4 = n >> 2;
    cvt_kernel<<<(n4 + 255) / 256, 256, 0, stream>>>(s, d, n4);
  };
  cvt(qkv_w, qkvw_b, 3 * ND * ND);
  cvt(o_w, ow_b, ND * ND);
  cvt(out_w, outw_b, ND * NSC);
  cvt(in_w, W1, NSC * ND);
  cvt(gate_w, W1 + (size_t)NSC * ND, NSC * ND);
  cvt(dt_w, W2, NSC * NSC);
  cvt(Bp_w, W2 + NSC * NSC, NST * NSC);
  cvt(Cp_w, W2 + NSC * NSC + NST * NSC, NST * NSC);

  rmsnorm_kernel<<<NM, 256, 0, stream>>>(x, n1w, h);
  gemm_bt_kernel<false, false><<<dim3(3 * ND / 128, NM / 128), 256, 0, stream>>>(
      h, qkvw_b, nullptr, (void*)qkv, 3 * ND, ND, ND);
  attn_kernel<<<dim3(NT / 64, NB * NH), 256, 0, stream>>>(qkv, attnout);
  gemm_bt_kernel<true, true><<<dim3(ND / 128, NM / 128), 256, 0, stream>>>(
      attnout, ow_b, x, (void*)x1, ND, ND, ND);
  rmsnorm_kernel<<<NM, 256, 0, stream>>>(x1, n2w, h2);
  gemm_bt_kernel<false, false><<<dim3(1, NM / 128), 256, 0, stream>>>(
      h2, W1, nullptr, (void*)zg, 128, ND, ND);
  gemm_bt_kernel<false, true><<<dim3(1, NM / 128), 256, 0, stream>>>(
      zg, W2, nullptr, (void*)P2, 128, NSC, 128);
  scanprep_kernel<<<NM / 4, 256, 0, stream>>>(zg, P2, dt_b, dt_a, dtz_a, gate_a);
  scan_kernel<<<NB, 1024, 0, stream>>>(dt_a, dtz_a, P2, gate_a, A_log, ys);
  gemm_bt_kernel<true, true><<<dim3(ND / 128, NM / 128), 256, 0, stream>>>(
      ys, outw_b, x1, (void*)out, ND, NSC, NSC);
}

// Round 4
// 417.719 us; speedup vs baseline: 4.0428x; 4.0428x over previous
//
#include <hip/hip_runtime.h>
#include <hip/hip_bf16.h>
#include <math.h>

typedef __hip_bfloat16 bf16;
typedef __attribute__((ext_vector_type(4))) float v_f32x4;
typedef __attribute__((ext_vector_type(4))) unsigned short v_u16x4;
typedef __attribute__((ext_vector_type(8))) unsigned short v_u16x8;
typedef __attribute__((ext_vector_type(8))) __bf16 v_bf16x8;

#define NB 2
#define NT 2048
#define ND 1024
#define NH 16
#define NSC 64
#define NST 16
#define NM (NB*NT)
#define RMS_EPS 1.1920929e-07f
#define NCHUNK 32
#define CLEN 64

__device__ inline float b2f(unsigned short u) {
  union { unsigned int i; float f; } v; v.i = ((unsigned int)u) << 16; return v.f;
}
__device__ inline unsigned short f2b(float f) {  // RNE f32->bf16
  union { float f; unsigned int i; } v; v.f = f;
  unsigned int r = (v.i + 0x7FFF + ((v.i >> 16) & 1)) >> 16;
  return (unsigned short)r;
}

// async global->LDS, 16B per lane; LDS dest = wave-uniform base + lane*16
__device__ inline void gl_lds16(const bf16* g, bf16* l) {
  __builtin_amdgcn_global_load_lds((__attribute__((address_space(1))) void*)g,
                                   (__attribute__((address_space(3))) void*)l,
                                   16, 0, 0);
}

// ---------------- f32 -> bf16 conversion (weights) ----------------
__global__ __launch_bounds__(256) void cvt_kernel(const float* __restrict__ src,
                                                  bf16* __restrict__ dst, int n4) {
  int i = blockIdx.x * 256 + threadIdx.x;
  if (i < n4) {
    v_f32x4 v = ((const v_f32x4*)src)[i];
    v_u16x4 o;
    o[0] = f2b(v[0]); o[1] = f2b(v[1]); o[2] = f2b(v[2]); o[3] = f2b(v[3]);
    ((v_u16x4*)dst)[i] = o;
  }
}

// ---------------- RMSNorm: f32 in, f32 weight, bf16 out ----------------
__global__ __launch_bounds__(256) void rmsnorm_kernel(
    const float* __restrict__ x, const float* __restrict__ w, bf16* __restrict__ out) {
  const int row = blockIdx.x;
  const int t = threadIdx.x;
  v_f32x4 xv = *(const v_f32x4*)(x + (size_t)row * ND + t * 4);
  float s = xv[0]*xv[0] + xv[1]*xv[1] + xv[2]*xv[2] + xv[3]*xv[3];
  #pragma unroll
  for (int off = 32; off; off >>= 1) s += __shfl_xor(s, off, 64);
  __shared__ float red[4];
  __shared__ float scale_s;
  if ((t & 63) == 0) red[t >> 6] = s;
  __syncthreads();
  if (t == 0) {
    float tot = red[0] + red[1] + red[2] + red[3];
    scale_s = rsqrtf(tot * (1.0f / ND) + RMS_EPS);
  }
  __syncthreads();
  float sc = scale_s;
  v_f32x4 wv = *(const v_f32x4*)(w + t * 4);
  unsigned short* orow = (unsigned short*)out + (size_t)row * ND + t * 4;
  v_u16x4 o;
  o[0] = f2b(xv[0] * sc * wv[0]);
  o[1] = f2b(xv[1] * sc * wv[1]);
  o[2] = f2b(xv[2] * sc * wv[2]);
  o[3] = f2b(xv[3] * sc * wv[3]);
  *(v_u16x4*)orow = o;
}

// ---------------- GEMM: C[M,N] = A[M,K(lda)] @ Bw[N,K]^T (+res f32) ----------------
template <bool RES, bool OUTF32>
__global__ __launch_bounds__(256) void gemm_bt_kernel(
    const bf16* __restrict__ A, const bf16* __restrict__ Bw,
    const float* __restrict__ res, void* __restrict__ Cout, int N, int K, int lda) {
  __shared__ alignas(16) bf16 As[128 * 32];
  __shared__ alignas(16) bf16 Bs[128 * 32];
  const int tid = threadIdx.x;
  const int wid = tid >> 6;
  const int lane = tid & 63;
  const int c = lane & 15;
  const int quad = lane >> 4;
  const int m0 = blockIdx.y * 128;
  const int n0 = blockIdx.x * 128;
  const int wm = (wid >> 1) * 64;
  const int wn = (wid & 1) * 64;
  const int srow = tid >> 2;
  const int schunk = tid & 3;

  const bf16* Ap0 = A + (size_t)(m0 + srow) * lda + schunk * 8;
  const bf16* Ap1 = Ap0 + (size_t)64 * lda;
  const bf16* Bp0 = Bw + (size_t)(n0 + srow) * K + schunk * 8;
  const bf16* Bp1 = Bp0 + (size_t)64 * K;
  bf16* AsW0 = As + wid * 512;
  bf16* AsW1 = As + 2048 + wid * 512;
  bf16* BsW0 = Bs + wid * 512;
  bf16* BsW1 = Bs + 2048 + wid * 512;

  v_f32x4 acc[4][4];
  #pragma unroll
  for (int i = 0; i < 4; i++)
    #pragma unroll
    for (int j = 0; j < 4; j++)
      #pragma unroll
      for (int r = 0; r < 4; r++) acc[i][j][r] = 0.0f;

  const int nk = K >> 5;
  for (int kt = 0; kt < nk; kt++) {
    gl_lds16(Ap0 + kt * 32, AsW0);
    gl_lds16(Ap1 + kt * 32, AsW1);
    gl_lds16(Bp0 + kt * 32, BsW0);
    gl_lds16(Bp1 + kt * 32, BsW1);
    __syncthreads();
    v_bf16x8 af[4], bfw[4];
    #pragma unroll
    for (int i = 0; i < 4; i++)
      af[i] = *(const v_bf16x8*)&As[(wm + i * 16 + c) * 32 + quad * 8];
    #pragma unroll
    for (int j = 0; j < 4; j++)
      bfw[j] = *(const v_bf16x8*)&Bs[(wn + j * 16 + c) * 32 + quad * 8];
    #pragma unroll
    for (int i = 0; i < 4; i++)
      #pragma unroll
      for (int j = 0; j < 4; j++)
        acc[i][j] = __builtin_amdgcn_mfma_f32_16x16x32_bf16(af[i], bfw[j], acc[i][j], 0, 0, 0);
    __syncthreads();
  }

  #pragma unroll
  for (int i = 0; i < 4; i++)
    #pragma unroll
    for (int j = 0; j < 4; j++)
      #pragma unroll
      for (int r = 0; r < 4; r++) {
        int rg = m0 + wm + i * 16 + quad * 4 + r;
        int cg = n0 + wn + j * 16 + c;
        size_t idx = (size_t)rg * N + cg;
        float v = acc[i][j][r];
        if (RES) v += res[idx];
        if (OUTF32) ((float*)Cout)[idx] = v;
        else ((bf16*)Cout)[idx] = __float2bfloat16(v);
      }
}

// ---------------- Flash attention (causal), MFMA QK^T and PV ----------------
__global__ __launch_bounds__(256) void attn_kernel(const bf16* __restrict__ qkv,
                                                   bf16* __restrict__ out) {
  __shared__ alignas(16) bf16 Qs[64 * 72];
  __shared__ alignas(16) bf16 Ks[64 * 72];
  __shared__ alignas(16) bf16 Vt[64 * 72];
  __shared__ alignas(16) bf16 Ps[64 * 72];
  const int tid = threadIdx.x;
  const int w = tid >> 6;
  const int lane = tid & 63;
  const int c = lane & 15;
  const int quad = lane >> 4;
  const int qt = blockIdx.x;
  const int bh = blockIdx.y;
  const int b = bh >> 4;
  const int h = bh & 15;
  const int srow = tid >> 2;
  const int schunk = tid & 3;

  {  // stage Q tile [64 q][64 d]
    const bf16* src = qkv + (size_t)(b * NT + qt * 64 + srow) * 3072 + h * 64 + schunk * 16;
    v_u16x8 v0 = *(const v_u16x8*)(src);
    v_u16x8 v1 = *(const v_u16x8*)(src + 8);
    *(v_u16x8*)&Qs[srow * 72 + schunk * 16] = v0;
    *(v_u16x8*)&Qs[srow * 72 + schunk * 16 + 8] = v1;
  }
  __syncthreads();
  v_bf16x8 aq0 = *(const v_bf16x8*)&Qs[(w * 16 + c) * 72 + quad * 8];
  v_bf16x8 aq1 = *(const v_bf16x8*)&Qs[(w * 16 + c) * 72 + 32 + quad * 8];

  float m[4], l[4];
  v_f32x4 o[4];
  #pragma unroll
  for (int r = 0; r < 4; r++) { m[r] = -__builtin_inff(); l[r] = 0.0f; }
  #pragma unroll
  for (int j = 0; j < 4; j++)
    #pragma unroll
    for (int r = 0; r < 4; r++) o[j][r] = 0.0f;

  unsigned short* Vtu = (unsigned short*)Vt;

  for (int kt = 0; kt <= qt; kt++) {
    {  // stage K [64 k][64 d] and V transposed [64 d][64 k]
      const bf16* ksrc = qkv + (size_t)(b * NT + kt * 64 + srow) * 3072 + 1024 + h * 64 + schunk * 16;
      v_u16x8 k0 = *(const v_u16x8*)(ksrc);
      v_u16x8 k1 = *(const v_u16x8*)(ksrc + 8);
      *(v_u16x8*)&Ks[srow * 72 + schunk * 16] = k0;
      *(v_u16x8*)&Ks[srow * 72 + schunk * 16 + 8] = k1;
      const bf16* vsrc = qkv + (size_t)(b * NT + kt * 64 + srow) * 3072 + 2048 + h * 64 + schunk * 16;
      v_u16x8 vv0 = *(const v_u16x8*)(vsrc);
      v_u16x8 vv1 = *(const v_u16x8*)(vsrc + 8);
      #pragma unroll
      for (int dd = 0; dd < 8; dd++) Vtu[(schunk * 16 + dd) * 72 + srow] = vv0[dd];
      #pragma unroll
      for (int dd = 0; dd < 8; dd++) Vtu[(schunk * 16 + dd + 8) * 72 + srow] = vv1[dd];
    }
    __syncthreads();

    // S = Q K^T  (per wave: 16 q rows x 64 keys)
    float sv[4][4];
    const bool diag = (kt == qt);
    #pragma unroll
    for (int j = 0; j < 4; j++) {
      v_bf16x8 bk0 = *(const v_bf16x8*)&Ks[(j * 16 + c) * 72 + quad * 8];
      v_bf16x8 bk1 = *(const v_bf16x8*)&Ks[(j * 16 + c) * 72 + 32 + quad * 8];
      v_f32x4 z;
      #pragma unroll
      for (int r = 0; r < 4; r++) z[r] = 0.0f;
      z = __builtin_amdgcn_mfma_f32_16x16x32_bf16(aq0, bk0, z, 0, 0, 0);
      z = __builtin_amdgcn_mfma_f32_16x16x32_bf16(aq1, bk1, z, 0, 0, 0);
      #pragma unroll
      for (int r = 0; r < 4; r++) {
        float v = z[r] * 0.125f;
        if (diag && (j * 16 + c) > (w * 16 + quad * 4 + r)) v = -__builtin_inff();
        sv[j][r] = v;
      }
    }

    // online softmax per q row (row = quad*4+r, 16 key-lanes share a quad)
    float alpha[4], p[4][4];
    #pragma unroll
    for (int r = 0; r < 4; r++) {
      float tm = fmaxf(fmaxf(sv[0][r], sv[1][r]), fmaxf(sv[2][r], sv[3][r]));
      #pragma unroll
      for (int off = 1; off < 16; off <<= 1) tm = fmaxf(tm, __shfl_xor(tm, off, 64));
      float mn = fmaxf(m[r], tm);
      alpha[r] = __expf(m[r] - mn);
      float ps = 0.0f;
      #pragma unroll
      for (int j = 0; j < 4; j++) { float pv = __expf(sv[j][r] - mn); p[j][r] = pv; ps += pv; }
      #pragma unroll
      for (int off = 1; off < 16; off <<= 1) ps += __shfl_xor(ps, off, 64);
      l[r] = l[r] * alpha[r] + ps;
      m[r] = mn;
    }
    // write P (C-layout -> LDS -> A-layout), rescale O
    #pragma unroll
    for (int j = 0; j < 4; j++)
      #pragma unroll
      for (int r = 0; r < 4; r++) {
        Ps[(w * 16 + quad * 4 + r) * 72 + j * 16 + c] = __float2bfloat16(p[j][r]);
        o[j][r] *= alpha[r];
      }
    // O += P V
    #pragma unroll
    for (int ks = 0; ks < 2; ks++) {
      v_bf16x8 ap = *(const v_bf16x8*)&Ps[(w * 16 + c) * 72 + ks * 32 + quad * 8];
      #pragma unroll
      for (int jn = 0; jn < 4; jn++) {
        v_bf16x8 bv = *(const v_bf16x8*)&Vt[(jn * 16 + c) * 72 + ks * 32 + quad * 8];
        o[jn] = __builtin_amdgcn_mfma_f32_16x16x32_bf16(ap, bv, o[jn], 0, 0, 0);
      }
    }
    __syncthreads();
  }

  #pragma unroll
  for (int jn = 0; jn < 4; jn++)
    #pragma unroll
    for (int r = 0; r < 4; r++) {
      int qg = qt * 64 + w * 16 + quad * 4 + r;
      out[(size_t)(b * NT + qg) * ND + h * 64 + jn * 16 + c] =
          __float2bfloat16(o[jn][r] / l[r]);
    }
}

// ---------------- scan prep: softplus/silu/dtz from zg + P2 ----------------
__global__ __launch_bounds__(256) void scanprep_kernel(
    const bf16* __restrict__ zg, const float* __restrict__ P2, const float* __restrict__ dt_b,
    float* __restrict__ dt_a, float* __restrict__ dtz_a, float* __restrict__ gate_a) {
  const int row = blockIdx.x * 4 + (threadIdx.x >> 6);
  const int c = threadIdx.x & 63;
  const unsigned short* zgu = (const unsigned short*)zg;
  float z = b2f(zgu[(size_t)row * 128 + c]);
  float g = b2f(zgu[(size_t)row * 128 + 64 + c]);
  float a = P2[(size_t)row * 128 + c] + dt_b[c];
  float dt = (a > 20.0f) ? a : log1pf(__expf(a));
  dt_a[(size_t)row * NSC + c] = dt;
  dtz_a[(size_t)row * NSC + c] = dt * z;
  gate_a[(size_t)row * NSC + c] = g / (1.0f + __expf(-g));
}

// ---------------- chunked parallel scan ----------------
// chains: [b][sc][st] = 2*64*16 = 2048.  chunk k covers t in [k*64, k*64+64)
// phase A: per (b, scg, k) block: local scan from 0 -> (P = prod a, S = end state)
__global__ __launch_bounds__(256) void scanA_kernel(
    const float* __restrict__ dt_a, const float* __restrict__ dtz_a,
    const float* __restrict__ P2, const float* __restrict__ A_log,
    float* __restrict__ Pbuf, float* __restrict__ Sbuf) {
  __shared__ float dtS[CLEN * 16], dtzS[CLEN * 16], biS[CLEN * 16];
  const int k = blockIdx.x, scg = blockIdx.y, b = blockIdx.z;
  const int tid = threadIdx.x;
  const int t0 = k * CLEN;
  {
    int r = tid >> 2, c4 = (tid & 3) * 4;
    *(v_f32x4*)&dtS[r * 16 + c4]  = *(const v_f32x4*)&dt_a[(size_t)(b * NT + t0 + r) * NSC + scg * 16 + c4];
    *(v_f32x4*)&dtzS[r * 16 + c4] = *(const v_f32x4*)&dtz_a[(size_t)(b * NT + t0 + r) * NSC + scg * 16 + c4];
    *(v_f32x4*)&biS[r * 16 + c4]  = *(const v_f32x4*)&P2[(size_t)(b * NT + t0 + r) * 128 + 64 + c4];
  }
  __syncthreads();
  const int st = tid & 15, scl = tid >> 4;
  const float A = -__expf(A_log[(scg * 16 + scl) * NST + st]);
  float P = 1.0f, s = 0.0f;
  #pragma unroll
  for (int t = 0; t < CLEN; t++) {
    float a = fmaf(dtS[t * 16 + scl], A, 1.0f);
    float u = dtzS[t * 16 + scl] * biS[t * 16 + st];
    P *= a;
    s = fmaf(a, s, u);
  }
  size_t idx = (size_t)(b * NCHUNK + k) * 1024 + scg * 256 + tid;
  Pbuf[idx] = P;
  Sbuf[idx] = s;
}

// phase B: per-chain sequential combine over 32 chunks -> chunk-initial states
__global__ __launch_bounds__(1024) void scanB_kernel(
    const float* __restrict__ Pbuf, const float* __restrict__ Sbuf,
    float* __restrict__ init) {
  const int b = blockIdx.x;
  const int tid = threadIdx.x;
  float P[NCHUNK], S[NCHUNK];
  #pragma unroll
  for (int kk = 0; kk < NCHUNK; kk++) {
    size_t idx = (size_t)(b * NCHUNK + kk) * 1024 + tid;
    P[kk] = Pbuf[idx];
    S[kk] = Sbuf[idx];
  }
  float s = 0.0f;
  #pragma unroll
  for (int kk = 0; kk < NCHUNK; kk++) {
    init[(size_t)(b * NCHUNK + kk) * 1024 + tid] = s;
    s = fmaf(P[kk], s, S[kk]);
  }
}

// phase C: re-scan each chunk from its true initial state; fused C-proj + gate + bf16 store
__global__ __launch_bounds__(256) void scanC_kernel(
    const float* __restrict__ dt_a, const float* __restrict__ dtz_a,
    const float* __restrict__ P2, const float* __restrict__ gate_a,
    const float* __restrict__ A_log, const float* __restrict__ init,
    bf16* __restrict__ ys) {
  __shared__ float dtS[CLEN * 16], dtzS[CLEN * 16], biS[CLEN * 16], ciS[CLEN * 16], gS[CLEN * 16];
  const int k = blockIdx.x, scg = blockIdx.y, b = blockIdx.z;
  const int tid = threadIdx.x;
  const int t0 = k * CLEN;
  {
    int r = tid >> 2, c4 = (tid & 3) * 4;
    *(v_f32x4*)&dtS[r * 16 + c4]  = *(const v_f32x4*)&dt_a[(size_t)(b * NT + t0 + r) * NSC + scg * 16 + c4];
    *(v_f32x4*)&dtzS[r * 16 + c4] = *(const v_f32x4*)&dtz_a[(size_t)(b * NT + t0 + r) * NSC + scg * 16 + c4];
    *(v_f32x4*)&biS[r * 16 + c4]  = *(const v_f32x4*)&P2[(size_t)(b * NT + t0 + r) * 128 + 64 + c4];
    *(v_f32x4*)&ciS[r * 16 + c4]  = *(const v_f32x4*)&P2[(size_t)(b * NT + t0 + r) * 128 + 80 + c4];
    *(v_f32x4*)&gS[r * 16 + c4]   = *(const v_f32x4*)&gate_a[(size_t)(b * NT + t0 + r) * NSC + scg * 16 + c4];
  }
  __syncthreads();
  const int st = tid & 15, scl = tid >> 4;
  const float A = -__expf(A_log[(scg * 16 + scl) * NST + st]);
  float s = init[(size_t)(b * NCHUNK + k) * 1024 + scg * 256 + tid];
  for (int t = 0; t < CLEN; t++) {
    float a = fmaf(dtS[t * 16 + scl], A, 1.0f);
    float u = dtzS[t * 16 + scl] * biS[t * 16 + st];
    s = fmaf(a, s, u);
    float pv = s * ciS[t * 16 + st];
    pv += __shfl_xor(pv, 1, 64);
    pv += __shfl_xor(pv, 2, 64);
    pv += __shfl_xor(pv, 4, 64);
    pv += __shfl_xor(pv, 8, 64);
    if (st == 0)
      ys[(size_t)(b * NT + t0 + t) * NSC + scg * 16 + scl] = __float2bfloat16(pv * gS[t * 16 + scl]);
  }
}

extern "C" void kernel_launch(void* const* d_in, const int* in_sizes, int n_in,
                              void* d_out, int out_size, void* d_ws, size_t ws_size,
                              hipStream_t stream) {
  // ALL inputs are float32 (per reference); output float32.
  const float* x      = (const float*)d_in[0];
  const float* qkv_w  = (const float*)d_in[1];
  const float* o_w    = (const float*)d_in[2];
  const float* n1w    = (const float*)d_in[3];
  const float* n2w    = (const float*)d_in[4];
  const float* in_w   = (const float*)d_in[5];
  const float* out_w  = (const float*)d_in[6];
  const float* A_log  = (const float*)d_in[7];
  const float* Bp_w   = (const float*)d_in[8];
  const float* Cp_w   = (const float*)d_in[9];
  const float* dt_w   = (const float*)d_in[10];
  const float* dt_b   = (const float*)d_in[11];
  const float* gate_w = (const float*)d_in[12];
  float* out = (float*)d_out;

  char* ws = (char*)d_ws;
  size_t off = 0;
  auto alloc = [&](size_t bytes) {
    char* p = ws + off;
    off += (bytes + 255) & ~(size_t)255;
    return p;
  };
  bf16* qkvw_b = (bf16*)alloc((size_t)3 * ND * ND * 2);   // 6 MB
  bf16* ow_b   = (bf16*)alloc((size_t)ND * ND * 2);       // 2 MB
  bf16* outw_b = (bf16*)alloc((size_t)ND * NSC * 2);      // 128 KB
  bf16* W1     = (bf16*)alloc((size_t)128 * ND * 2);      // 256 KB  (in_w rows 0-63, gate_w rows 64-127)
  bf16* W2     = (bf16*)alloc((size_t)128 * NSC * 2);     // 16 KB   (dt_w 0-63, Bp_w 64-79, Cp_w 80-95, zero tail)
  char* region0 = alloc((size_t)NM * 3 * ND * 2);         // 24 MB: qkv bf16, then x1 f32 (16 MB)
  char* region1 = alloc((size_t)NM * ND * 2);             // 8 MB: h -> attnout -> h2
  bf16*  zg    = (bf16*)alloc((size_t)NM * 128 * 2);      // 1 MB
  float* P2    = (float*)alloc((size_t)NM * 128 * 4);     // 2 MB
  float* dt_a  = (float*)alloc((size_t)NM * NSC * 4);     // 1 MB
  float* dtz_a = (float*)alloc((size_t)NM * NSC * 4);     // 1 MB
  float* gate_a= (float*)alloc((size_t)NM * NSC * 4);     // 1 MB
  bf16*  ys    = (bf16*)alloc((size_t)NM * NSC * 2);      // 512 KB
  float* Pbuf  = (float*)alloc((size_t)NB * NCHUNK * 1024 * 4);  // 256 KB
  float* Sbuf  = (float*)alloc((size_t)NB * NCHUNK * 1024 * 4);  // 256 KB
  float* initb = (float*)alloc((size_t)NB * NCHUNK * 1024 * 4);  // 256 KB

  bf16*  qkv     = (bf16*)region0;
  float* x1      = (float*)region0;   // aliases qkv (dead after attn)
  bf16*  h       = (bf16*)region1;
  bf16*  attnout = (bf16*)region1;    // aliases h (dead after qkv gemm)
  bf16*  h2      = (bf16*)region1;    // aliases attnout (dead after o gemm)

  // weight conversions (every launch; no static state)
  hipMemsetAsync(W2, 0, (size_t)128 * NSC * 2, stream);
  auto cvt = [&](const float* s, bf16* d, int n) {
    int n4 = n >> 2;
    cvt_kernel<<<(n4 + 255) / 256, 256, 0, stream>>>(s, d, n4);
  };
  cvt(qkv_w, qkvw_b, 3 * ND * ND);
  cvt(o_w, ow_b, ND * ND);
  cvt(out_w, outw_b, ND * NSC);
  cvt(in_w, W1, NSC * ND);
  cvt(gate_w, W1 + (size_t)NSC * ND, NSC * ND);
  cvt(dt_w, W2, NSC * NSC);
  cvt(Bp_w, W2 + NSC * NSC, NST * NSC);
  cvt(Cp_w, W2 + NSC * NSC + NST * NSC, NST * NSC);

  rmsnorm_kernel<<<NM, 256, 0, stream>>>(x, n1w, h);
  gemm_bt_kernel<false, false><<<dim3(3 * ND / 128, NM / 128), 256, 0, stream>>>(
      h, qkvw_b, nullptr, (void*)qkv, 3 * ND, ND, ND);
  attn_kernel<<<dim3(NT / 64, NB * NH), 256, 0, stream>>>(qkv, attnout);
  gemm_bt_kernel<true, true><<<dim3(ND / 128, NM / 128), 256, 0, stream>>>(
      attnout, ow_b, x, (void*)x1, ND, ND, ND);
  rmsnorm_kernel<<<NM, 256, 0, stream>>>(x1, n2w, h2);
  gemm_bt_kernel<false, false><<<dim3(1, NM / 128), 256, 0, stream>>>(
      h2, W1, nullptr, (void*)zg, 128, ND, ND);
  gemm_bt_kernel<false, true><<<dim3(1, NM / 128), 256, 0, stream>>>(
      zg, W2, nullptr, (void*)P2, 128, NSC, 128);
  scanprep_kernel<<<NM / 4, 256, 0, stream>>>(zg, P2, dt_b, dt_a, dtz_a, gate_a);
  scanA_kernel<<<dim3(NCHUNK, 4, NB), 256, 0, stream>>>(dt_a, dtz_a, P2, A_log, Pbuf, Sbuf);
  scanB_kernel<<<NB, 1024, 0, stream>>>(Pbuf, Sbuf, initb);
  scanC_kernel<<<dim3(NCHUNK, 4, NB), 256, 0, stream>>>(dt_a, dtz_a, P2, gate_a, A_log, initb, ys);
  gemm_bt_kernel<true, true><<<dim3(ND / 128, NM / 128), 256, 0, stream>>>(
      ys, outw_b, x1, (void*)out, ND, NSC, NSC);
}

// Round 5
// 299.467 us; speedup vs baseline: 5.6392x; 1.3949x over previous
//
#include <hip/hip_runtime.h>
#include <hip/hip_bf16.h>
#include <math.h>

typedef __hip_bfloat16 bf16;
typedef __attribute__((ext_vector_type(4))) float v_f32x4;
typedef __attribute__((ext_vector_type(4))) unsigned short v_u16x4;
typedef __attribute__((ext_vector_type(8))) unsigned short v_u16x8;
typedef __attribute__((ext_vector_type(8))) __bf16 v_bf16x8;

#define NB 2
#define NT 2048
#define ND 1024
#define NH 16
#define NSC 64
#define NST 16
#define NM (NB*NT)
#define RMS_EPS 1.1920929e-07f
#define NCHUNK 32
#define CLEN 64

__device__ inline float b2f(unsigned short u) {
  union { unsigned int i; float f; } v; v.i = ((unsigned int)u) << 16; return v.f;
}
__device__ inline unsigned short f2b(float f) {  // RNE f32->bf16
  union { float f; unsigned int i; } v; v.f = f;
  unsigned int r = (v.i + 0x7FFF + ((v.i >> 16) & 1)) >> 16;
  return (unsigned short)r;
}

// async global->LDS, 16B per lane; LDS dest = wave-uniform base + lane*16
__device__ inline void gl_lds16(const bf16* g, bf16* l) {
  __builtin_amdgcn_global_load_lds((__attribute__((address_space(1))) void*)g,
                                   (__attribute__((address_space(3))) void*)l,
                                   16, 0, 0);
}

// ---------------- f32 -> bf16 conversion (weights) ----------------
__global__ __launch_bounds__(256) void cvt_kernel(const float* __restrict__ src,
                                                  bf16* __restrict__ dst, int n4) {
  int i = blockIdx.x * 256 + threadIdx.x;
  if (i < n4) {
    v_f32x4 v = ((const v_f32x4*)src)[i];
    v_u16x4 o;
    o[0] = f2b(v[0]); o[1] = f2b(v[1]); o[2] = f2b(v[2]); o[3] = f2b(v[3]);
    ((v_u16x4*)dst)[i] = o;
  }
}

// ---------------- RMSNorm: f32 in, f32 weight, bf16 out ----------------
__global__ __launch_bounds__(256) void rmsnorm_kernel(
    const float* __restrict__ x, const float* __restrict__ w, bf16* __restrict__ out) {
  const int row = blockIdx.x;
  const int t = threadIdx.x;
  v_f32x4 xv = *(const v_f32x4*)(x + (size_t)row * ND + t * 4);
  float s = xv[0]*xv[0] + xv[1]*xv[1] + xv[2]*xv[2] + xv[3]*xv[3];
  #pragma unroll
  for (int off = 32; off; off >>= 1) s += __shfl_xor(s, off, 64);
  __shared__ float red[4];
  __shared__ float scale_s;
  if ((t & 63) == 0) red[t >> 6] = s;
  __syncthreads();
  if (t == 0) {
    float tot = red[0] + red[1] + red[2] + red[3];
    scale_s = rsqrtf(tot * (1.0f / ND) + RMS_EPS);
  }
  __syncthreads();
  float sc = scale_s;
  v_f32x4 wv = *(const v_f32x4*)(w + t * 4);
  unsigned short* orow = (unsigned short*)out + (size_t)row * ND + t * 4;
  v_u16x4 o;
  o[0] = f2b(xv[0] * sc * wv[0]);
  o[1] = f2b(xv[1] * sc * wv[1]);
  o[2] = f2b(xv[2] * sc * wv[2]);
  o[3] = f2b(xv[3] * sc * wv[3]);
  *(v_u16x4*)orow = o;
}

// ---------------- GEMM: C[M,N] = A[M,K(lda)] @ Bw[N,K]^T (+res f32) ----------------
template <bool RES, bool OUTF32>
__global__ __launch_bounds__(256) void gemm_bt_kernel(
    const bf16* __restrict__ A, const bf16* __restrict__ Bw,
    const float* __restrict__ res, void* __restrict__ Cout, int N, int K, int lda) {
  __shared__ alignas(16) bf16 As[128 * 32];
  __shared__ alignas(16) bf16 Bs[128 * 32];
  const int tid = threadIdx.x;
  const int wid = tid >> 6;
  const int lane = tid & 63;
  const int c = lane & 15;
  const int quad = lane >> 4;
  const int m0 = blockIdx.y * 128;
  const int n0 = blockIdx.x * 128;
  const int wm = (wid >> 1) * 64;
  const int wn = (wid & 1) * 64;
  const int srow = tid >> 2;
  const int schunk = tid & 3;

  const bf16* Ap0 = A + (size_t)(m0 + srow) * lda + schunk * 8;
  const bf16* Ap1 = Ap0 + (size_t)64 * lda;
  const bf16* Bp0 = Bw + (size_t)(n0 + srow) * K + schunk * 8;
  const bf16* Bp1 = Bp0 + (size_t)64 * K;
  bf16* AsW0 = As + wid * 512;
  bf16* AsW1 = As + 2048 + wid * 512;
  bf16* BsW0 = Bs + wid * 512;
  bf16* BsW1 = Bs + 2048 + wid * 512;

  v_f32x4 acc[4][4];
  #pragma unroll
  for (int i = 0; i < 4; i++)
    #pragma unroll
    for (int j = 0; j < 4; j++)
      #pragma unroll
      for (int r = 0; r < 4; r++) acc[i][j][r] = 0.0f;

  const int nk = K >> 5;
  for (int kt = 0; kt < nk; kt++) {
    gl_lds16(Ap0 + kt * 32, AsW0);
    gl_lds16(Ap1 + kt * 32, AsW1);
    gl_lds16(Bp0 + kt * 32, BsW0);
    gl_lds16(Bp1 + kt * 32, BsW1);
    __syncthreads();
    v_bf16x8 af[4], bfw[4];
    #pragma unroll
    for (int i = 0; i < 4; i++)
      af[i] = *(const v_bf16x8*)&As[(wm + i * 16 + c) * 32 + quad * 8];
    #pragma unroll
    for (int j = 0; j < 4; j++)
      bfw[j] = *(const v_bf16x8*)&Bs[(wn + j * 16 + c) * 32 + quad * 8];
    #pragma unroll
    for (int i = 0; i < 4; i++)
      #pragma unroll
      for (int j = 0; j < 4; j++)
        acc[i][j] = __builtin_amdgcn_mfma_f32_16x16x32_bf16(af[i], bfw[j], acc[i][j], 0, 0, 0);
    __syncthreads();
  }

  #pragma unroll
  for (int i = 0; i < 4; i++)
    #pragma unroll
    for (int j = 0; j < 4; j++)
      #pragma unroll
      for (int r = 0; r < 4; r++) {
        int rg = m0 + wm + i * 16 + quad * 4 + r;
        int cg = n0 + wn + j * 16 + c;
        size_t idx = (size_t)rg * N + cg;
        float v = acc[i][j][r];
        if (RES) v += res[idx];
        if (OUTF32) ((float*)Cout)[idx] = v;
        else ((bf16*)Cout)[idx] = __float2bfloat16(v);
      }
}

// ---------------- skinny GEMM: C[M,128] = A[M,K(lda)] @ Bw[128,K]^T, M-tile 16 ----------------
template <bool OUTF32>
__global__ __launch_bounds__(256) void gemm_skinny_kernel(
    const bf16* __restrict__ A, const bf16* __restrict__ Bw,
    void* __restrict__ Cout, int K, int lda) {
  __shared__ alignas(16) bf16 As[16 * 32];
  __shared__ alignas(16) bf16 Bs[128 * 32];
  const int tid = threadIdx.x;
  const int w = tid >> 6;
  const int lane = tid & 63;
  const int c = lane & 15;
  const int quad = lane >> 4;
  const int m0 = blockIdx.x * 16;
  const int lrow = lane >> 2, lchunk = lane & 3;

  const bf16* ApL = A + (size_t)(m0 + lrow) * lda + lchunk * 8;
  const bf16* BpL0 = Bw + (size_t)(w * 16 + lrow) * K + lchunk * 8;
  const bf16* BpL1 = Bw + (size_t)(64 + w * 16 + lrow) * K + lchunk * 8;
  bf16* BsW0 = Bs + w * 512;
  bf16* BsW1 = Bs + 2048 + w * 512;

  v_f32x4 acc[2];
  #pragma unroll
  for (int j = 0; j < 2; j++)
    #pragma unroll
    for (int r = 0; r < 4; r++) acc[j][r] = 0.0f;

  const int nk = K >> 5;
  for (int kt = 0; kt < nk; kt++) {
    if (w == 0) gl_lds16(ApL + kt * 32, As);
    gl_lds16(BpL0 + kt * 32, BsW0);
    gl_lds16(BpL1 + kt * 32, BsW1);
    __syncthreads();
    v_bf16x8 af = *(const v_bf16x8*)&As[c * 32 + quad * 8];
    #pragma unroll
    for (int j = 0; j < 2; j++) {
      v_bf16x8 bfw = *(const v_bf16x8*)&Bs[(w * 32 + j * 16 + c) * 32 + quad * 8];
      acc[j] = __builtin_amdgcn_mfma_f32_16x16x32_bf16(af, bfw, acc[j], 0, 0, 0);
    }
    __syncthreads();
  }

  #pragma unroll
  for (int j = 0; j < 2; j++)
    #pragma unroll
    for (int r = 0; r < 4; r++) {
      size_t idx = (size_t)(m0 + quad * 4 + r) * 128 + w * 32 + j * 16 + c;
      if (OUTF32) ((float*)Cout)[idx] = acc[j][r];
      else ((bf16*)Cout)[idx] = __float2bfloat16(acc[j][r]);
    }
}

// ---------------- V transpose: qkv V-part -> VtG[bh][d][t] ----------------
__global__ __launch_bounds__(256) void vtrans_kernel(const bf16* __restrict__ qkv,
                                                     bf16* __restrict__ VtG) {
  __shared__ alignas(16) bf16 Vs[64 * 72];
  const int tid = threadIdx.x;
  const int t0 = blockIdx.x * 64;
  const int bh = blockIdx.y;
  const int b = bh >> 4, h = bh & 15;
  const int srow = tid >> 2, schunk = tid & 3;
  {
    const bf16* src = qkv + (size_t)(b * NT + t0 + srow) * 3072 + 2048 + h * 64 + schunk * 16;
    *(v_u16x8*)&Vs[srow * 72 + schunk * 16] = *(const v_u16x8*)src;
    *(v_u16x8*)&Vs[srow * 72 + schunk * 16 + 8] = *(const v_u16x8*)(src + 8);
  }
  __syncthreads();
  const unsigned short* Vsu = (const unsigned short*)Vs;
  v_u16x8 a, bvec;
  #pragma unroll
  for (int i = 0; i < 8; i++) a[i] = Vsu[(schunk * 16 + i) * 72 + srow];
  #pragma unroll
  for (int i = 0; i < 8; i++) bvec[i] = Vsu[(schunk * 16 + 8 + i) * 72 + srow];
  bf16* dst = VtG + (size_t)(bh * 64 + srow) * NT + t0 + schunk * 16;
  *(v_u16x8*)dst = a;
  *(v_u16x8*)(dst + 8) = bvec;
}

// ---------------- Flash attention (causal), no-max softmax, MFMA QK^T and PV ----------------
__global__ __launch_bounds__(256) void attn_kernel(const bf16* __restrict__ qkv,
                                                   const bf16* __restrict__ VtG,
                                                   bf16* __restrict__ out) {
  __shared__ alignas(16) bf16 Qs[64 * 72];
  __shared__ alignas(16) bf16 Ks[64 * 72];
  __shared__ alignas(16) bf16 Vt[64 * 72];
  __shared__ alignas(16) bf16 Ps[64 * 72];
  const int tid = threadIdx.x;
  const int w = tid >> 6;
  const int lane = tid & 63;
  const int c = lane & 15;
  const int quad = lane >> 4;
  // balance swizzle: every CU's 4 round-robin blocks sum to the same iteration count
  const int id = blockIdx.x;
  const int bh = id & 31;
  const int j5 = id >> 5;
  const int j0 = j5 & 7;
  const int qt = (j5 & 24) | (((j5 >> 3) & 1) ? (7 - j0) : j0);
  const int b = bh >> 4;
  const int h = bh & 15;
  const int srow = tid >> 2;
  const int schunk = tid & 3;

  {  // stage Q tile [64 q][64 d]
    const bf16* src = qkv + (size_t)(b * NT + qt * 64 + srow) * 3072 + h * 64 + schunk * 16;
    *(v_u16x8*)&Qs[srow * 72 + schunk * 16] = *(const v_u16x8*)src;
    *(v_u16x8*)&Qs[srow * 72 + schunk * 16 + 8] = *(const v_u16x8*)(src + 8);
  }
  __syncthreads();
  v_bf16x8 aq0 = *(const v_bf16x8*)&Qs[(w * 16 + c) * 72 + quad * 8];
  v_bf16x8 aq1 = *(const v_bf16x8*)&Qs[(w * 16 + c) * 72 + 32 + quad * 8];

  float l_part[4];
  v_f32x4 o[4];
  #pragma unroll
  for (int r = 0; r < 4; r++) l_part[r] = 0.0f;
  #pragma unroll
  for (int j = 0; j < 4; j++)
    #pragma unroll
    for (int r = 0; r < 4; r++) o[j][r] = 0.0f;

  for (int kt = 0; kt <= qt; kt++) {
    {  // stage K [64 k][64 d] and Vt [64 d][64 k] (pre-transposed in global)
      const bf16* ksrc = qkv + (size_t)(b * NT + kt * 64 + srow) * 3072 + 1024 + h * 64 + schunk * 16;
      *(v_u16x8*)&Ks[srow * 72 + schunk * 16] = *(const v_u16x8*)ksrc;
      *(v_u16x8*)&Ks[srow * 72 + schunk * 16 + 8] = *(const v_u16x8*)(ksrc + 8);
      const bf16* vsrc = VtG + (size_t)(bh * 64 + srow) * NT + kt * 64 + schunk * 16;
      *(v_u16x8*)&Vt[srow * 72 + schunk * 16] = *(const v_u16x8*)vsrc;
      *(v_u16x8*)&Vt[srow * 72 + schunk * 16 + 8] = *(const v_u16x8*)(vsrc + 8);
    }
    __syncthreads();

    // S = Q K^T  (per wave: 16 q rows x 64 keys)
    const bool diag = (kt == qt);
    #pragma unroll
    for (int j = 0; j < 4; j++) {
      v_bf16x8 bk0 = *(const v_bf16x8*)&Ks[(j * 16 + c) * 72 + quad * 8];
      v_bf16x8 bk1 = *(const v_bf16x8*)&Ks[(j * 16 + c) * 72 + 32 + quad * 8];
      v_f32x4 z;
      #pragma unroll
      for (int r = 0; r < 4; r++) z[r] = 0.0f;
      z = __builtin_amdgcn_mfma_f32_16x16x32_bf16(aq0, bk0, z, 0, 0, 0);
      z = __builtin_amdgcn_mfma_f32_16x16x32_bf16(aq1, bk1, z, 0, 0, 0);
      // no-max softmax: p = exp(s) directly (logits << fp32 range; clamp = safety net)
      #pragma unroll
      for (int r = 0; r < 4; r++) {
        float s = fminf(z[r] * 0.125f, 60.0f);
        float p = __expf(s);
        if (diag && (j * 16 + c) > (w * 16 + quad * 4 + r)) p = 0.0f;
        l_part[r] += p;
        Ps[(w * 16 + quad * 4 + r) * 72 + j * 16 + c] = __float2bfloat16(p);
      }
    }
    // O += P V  (wave w reads only rows it wrote; in-wave lockstep, no barrier needed)
    #pragma unroll
    for (int ks = 0; ks < 2; ks++) {
      v_bf16x8 ap = *(const v_bf16x8*)&Ps[(w * 16 + c) * 72 + ks * 32 + quad * 8];
      #pragma unroll
      for (int jn = 0; jn < 4; jn++) {
        v_bf16x8 bv = *(const v_bf16x8*)&Vt[(jn * 16 + c) * 72 + ks * 32 + quad * 8];
        o[jn] = __builtin_amdgcn_mfma_f32_16x16x32_bf16(ap, bv, o[jn], 0, 0, 0);
      }
    }
    __syncthreads();
  }

  // reduce l across the 16 key-lanes (once)
  #pragma unroll
  for (int r = 0; r < 4; r++) {
    float l = l_part[r];
    l += __shfl_xor(l, 1, 64);
    l += __shfl_xor(l, 2, 64);
    l += __shfl_xor(l, 4, 64);
    l += __shfl_xor(l, 8, 64);
    l_part[r] = l;
  }

  #pragma unroll
  for (int jn = 0; jn < 4; jn++)
    #pragma unroll
    for (int r = 0; r < 4; r++) {
      int qg = qt * 64 + w * 16 + quad * 4 + r;
      out[(size_t)(b * NT + qg) * ND + h * 64 + jn * 16 + c] =
          __float2bfloat16(o[jn][r] / l_part[r]);
    }
}

// ---------------- scan prep: softplus/silu/dtz from zg + P2 ----------------
__global__ __launch_bounds__(256) void scanprep_kernel(
    const bf16* __restrict__ zg, const float* __restrict__ P2, const float* __restrict__ dt_b,
    float* __restrict__ dt_a, float* __restrict__ dtz_a, float* __restrict__ gate_a) {
  const int row = blockIdx.x * 4 + (threadIdx.x >> 6);
  const int c = threadIdx.x & 63;
  const unsigned short* zgu = (const unsigned short*)zg;
  float z = b2f(zgu[(size_t)row * 128 + c]);
  float g = b2f(zgu[(size_t)row * 128 + 64 + c]);
  float a = P2[(size_t)row * 128 + c] + dt_b[c];
  float dt = (a > 20.0f) ? a : log1pf(__expf(a));
  dt_a[(size_t)row * NSC + c] = dt;
  dtz_a[(size_t)row * NSC + c] = dt * z;
  gate_a[(size_t)row * NSC + c] = g / (1.0f + __expf(-g));
}

// ---------------- chunked parallel scan ----------------
__global__ __launch_bounds__(256) void scanA_kernel(
    const float* __restrict__ dt_a, const float* __restrict__ dtz_a,
    const float* __restrict__ P2, const float* __restrict__ A_log,
    float* __restrict__ Pbuf, float* __restrict__ Sbuf) {
  __shared__ float dtS[CLEN * 16], dtzS[CLEN * 16], biS[CLEN * 16];
  const int k = blockIdx.x, scg = blockIdx.y, b = blockIdx.z;
  const int tid = threadIdx.x;
  const int t0 = k * CLEN;
  {
    int r = tid >> 2, c4 = (tid & 3) * 4;
    *(v_f32x4*)&dtS[r * 16 + c4]  = *(const v_f32x4*)&dt_a[(size_t)(b * NT + t0 + r) * NSC + scg * 16 + c4];
    *(v_f32x4*)&dtzS[r * 16 + c4] = *(const v_f32x4*)&dtz_a[(size_t)(b * NT + t0 + r) * NSC + scg * 16 + c4];
    *(v_f32x4*)&biS[r * 16 + c4]  = *(const v_f32x4*)&P2[(size_t)(b * NT + t0 + r) * 128 + 64 + c4];
  }
  __syncthreads();
  const int st = tid & 15, scl = tid >> 4;
  const float A = -__expf(A_log[(scg * 16 + scl) * NST + st]);
  float P = 1.0f, s = 0.0f;
  #pragma unroll
  for (int t = 0; t < CLEN; t++) {
    float a = fmaf(dtS[t * 16 + scl], A, 1.0f);
    float u = dtzS[t * 16 + scl] * biS[t * 16 + st];
    P *= a;
    s = fmaf(a, s, u);
  }
  size_t idx = (size_t)(b * NCHUNK + k) * 1024 + scg * 256 + tid;
  Pbuf[idx] = P;
  Sbuf[idx] = s;
}

__global__ __launch_bounds__(1024) void scanB_kernel(
    const float* __restrict__ Pbuf, const float* __restrict__ Sbuf,
    float* __restrict__ init) {
  const int b = blockIdx.x;
  const int tid = threadIdx.x;
  float P[NCHUNK], S[NCHUNK];
  #pragma unroll
  for (int kk = 0; kk < NCHUNK; kk++) {
    size_t idx = (size_t)(b * NCHUNK + kk) * 1024 + tid;
    P[kk] = Pbuf[idx];
    S[kk] = Sbuf[idx];
  }
  float s = 0.0f;
  #pragma unroll
  for (int kk = 0; kk < NCHUNK; kk++) {
    init[(size_t)(b * NCHUNK + kk) * 1024 + tid] = s;
    s = fmaf(P[kk], s, S[kk]);
  }
}

__global__ __launch_bounds__(256) void scanC_kernel(
    const float* __restrict__ dt_a, const float* __restrict__ dtz_a,
    const float* __restrict__ P2, const float* __restrict__ gate_a,
    const float* __restrict__ A_log, const float* __restrict__ init,
    bf16* __restrict__ ys) {
  __shared__ float dtS[CLEN * 16], dtzS[CLEN * 16], biS[CLEN * 16], ciS[CLEN * 16], gS[CLEN * 16];
  const int k = blockIdx.x, scg = blockIdx.y, b = blockIdx.z;
  const int tid = threadIdx.x;
  const int t0 = k * CLEN;
  {
    int r = tid >> 2, c4 = (tid & 3) * 4;
    *(v_f32x4*)&dtS[r * 16 + c4]  = *(const v_f32x4*)&dt_a[(size_t)(b * NT + t0 + r) * NSC + scg * 16 + c4];
    *(v_f32x4*)&dtzS[r * 16 + c4] = *(const v_f32x4*)&dtz_a[(size_t)(b * NT + t0 + r) * NSC + scg * 16 + c4];
    *(v_f32x4*)&biS[r * 16 + c4]  = *(const v_f32x4*)&P2[(size_t)(b * NT + t0 + r) * 128 + 64 + c4];
    *(v_f32x4*)&ciS[r * 16 + c4]  = *(const v_f32x4*)&P2[(size_t)(b * NT + t0 + r) * 128 + 80 + c4];
    *(v_f32x4*)&gS[r * 16 + c4]   = *(const v_f32x4*)&gate_a[(size_t)(b * NT + t0 + r) * NSC + scg * 16 + c4];
  }
  __syncthreads();
  const int st = tid & 15, scl = tid >> 4;
  const float A = -__expf(A_log[(scg * 16 + scl) * NST + st]);
  float s = init[(size_t)(b * NCHUNK + k) * 1024 + scg * 256 + tid];
  for (int t = 0; t < CLEN; t++) {
    float a = fmaf(dtS[t * 16 + scl], A, 1.0f);
    float u = dtzS[t * 16 + scl] * biS[t * 16 + st];
    s = fmaf(a, s, u);
    float pv = s * ciS[t * 16 + st];
    pv += __shfl_xor(pv, 1, 64);
    pv += __shfl_xor(pv, 2, 64);
    pv += __shfl_xor(pv, 4, 64);
    pv += __shfl_xor(pv, 8, 64);
    if (st == 0)
      ys[(size_t)(b * NT + t0 + t) * NSC + scg * 16 + scl] = __float2bfloat16(pv * gS[t * 16 + scl]);
  }
}

extern "C" void kernel_launch(void* const* d_in, const int* in_sizes, int n_in,
                              void* d_out, int out_size, void* d_ws, size_t ws_size,
                              hipStream_t stream) {
  const float* x      = (const float*)d_in[0];
  const float* qkv_w  = (const float*)d_in[1];
  const float* o_w    = (const float*)d_in[2];
  const float* n1w    = (const float*)d_in[3];
  const float* n2w    = (const float*)d_in[4];
  const float* in_w   = (const float*)d_in[5];
  const float* out_w  = (const float*)d_in[6];
  const float* A_log  = (const float*)d_in[7];
  const float* Bp_w   = (const float*)d_in[8];
  const float* Cp_w   = (const float*)d_in[9];
  const float* dt_w   = (const float*)d_in[10];
  const float* dt_b   = (const float*)d_in[11];
  const float* gate_w = (const float*)d_in[12];
  float* out = (float*)d_out;

  char* ws = (char*)d_ws;
  size_t off = 0;
  auto alloc = [&](size_t bytes) {
    char* p = ws + off;
    off += (bytes + 255) & ~(size_t)255;
    return p;
  };
  bf16* qkvw_b = (bf16*)alloc((size_t)3 * ND * ND * 2);   // 6 MB
  bf16* ow_b   = (bf16*)alloc((size_t)ND * ND * 2);       // 2 MB
  bf16* outw_b = (bf16*)alloc((size_t)ND * NSC * 2);      // 128 KB
  bf16* W1     = (bf16*)alloc((size_t)128 * ND * 2);      // 256 KB
  bf16* W2     = (bf16*)alloc((size_t)128 * NSC * 2);     // 16 KB
  char* region0 = alloc((size_t)NM * 3 * ND * 2);         // 24 MB: qkv bf16 -> x1 f32
  char* region1 = alloc((size_t)NM * ND * 2);             // 8 MB: h -> attnout -> h2
  bf16* VtG    = (bf16*)alloc((size_t)NB * NH * 64 * NT * 2);  // 8 MB
  bf16*  zg    = (bf16*)alloc((size_t)NM * 128 * 2);      // 1 MB
  float* P2    = (float*)alloc((size_t)NM * 128 * 4);     // 2 MB
  float* dt_a  = (float*)alloc((size_t)NM * NSC * 4);     // 1 MB
  float* dtz_a = (float*)alloc((size_t)NM * NSC * 4);     // 1 MB
  float* gate_a= (float*)alloc((size_t)NM * NSC * 4);     // 1 MB
  bf16*  ys    = (bf16*)alloc((size_t)NM * NSC * 2);      // 512 KB
  float* Pbuf  = (float*)alloc((size_t)NB * NCHUNK * 1024 * 4);
  float* Sbuf  = (float*)alloc((size_t)NB * NCHUNK * 1024 * 4);
  float* initb = (float*)alloc((size_t)NB * NCHUNK * 1024 * 4);

  bf16*  qkv     = (bf16*)region0;
  float* x1      = (float*)region0;   // aliases qkv (dead after attn)
  bf16*  h       = (bf16*)region1;
  bf16*  attnout = (bf16*)region1;    // aliases h (dead after qkv gemm)
  bf16*  h2      = (bf16*)region1;    // aliases attnout (dead after o gemm)

  hipMemsetAsync(W2, 0, (size_t)128 * NSC * 2, stream);
  auto cvt = [&](const float* s, bf16* d, int n) {
    int n4 = n >> 2;
    cvt_kernel<<<(n4 + 255) / 256, 256, 0, stream>>>(s, d, n4);
  };
  cvt(qkv_w, qkvw_b, 3 * ND * ND);
  cvt(o_w, ow_b, ND * ND);
  cvt(out_w, outw_b, ND * NSC);
  cvt(in_w, W1, NSC * ND);
  cvt(gate_w, W1 + (size_t)NSC * ND, NSC * ND);
  cvt(dt_w, W2, NSC * NSC);
  cvt(Bp_w, W2 + NSC * NSC, NST * NSC);
  cvt(Cp_w, W2 + NSC * NSC + NST * NSC, NST * NSC);

  rmsnorm_kernel<<<NM, 256, 0, stream>>>(x, n1w, h);
  gemm_bt_kernel<false, false><<<dim3(3 * ND / 128, NM / 128), 256, 0, stream>>>(
      h, qkvw_b, nullptr, (void*)qkv, 3 * ND, ND, ND);
  vtrans_kernel<<<dim3(NT / 64, NB * NH), 256, 0, stream>>>(qkv, VtG);
  attn_kernel<<<(NT / 64) * NB * NH, 256, 0, stream>>>(qkv, VtG, attnout);
  gemm_bt_kernel<true, true><<<dim3(ND / 128, NM / 128), 256, 0, stream>>>(
      attnout, ow_b, x, (void*)x1, ND, ND, ND);
  rmsnorm_kernel<<<NM, 256, 0, stream>>>(x1, n2w, h2);
  gemm_skinny_kernel<false><<<NM / 16, 256, 0, stream>>>(h2, W1, (void*)zg, ND, ND);
  gemm_skinny_kernel<true><<<NM / 16, 256, 0, stream>>>(zg, W2, (void*)P2, NSC, 128);
  scanprep_kernel<<<NM / 4, 256, 0, stream>>>(zg, P2, dt_b, dt_a, dtz_a, gate_a);
  scanA_kernel<<<dim3(NCHUNK, 4, NB), 256, 0, stream>>>(dt_a, dtz_a, P2, A_log, Pbuf, Sbuf);
  scanB_kernel<<<NB, 1024, 0, stream>>>(Pbuf, Sbuf, initb);
  scanC_kernel<<<dim3(NCHUNK, 4, NB), 256, 0, stream>>>(dt_a, dtz_a, P2, gate_a, A_log, initb, ys);
  gemm_bt_kernel<true, true><<<dim3(ND / 128, NM / 128), 256, 0, stream>>>(
      ys, outw_b, x1, (void*)out, ND, NSC, NSC);
}